// Round 1
// baseline (859.172 us; speedup 1.0000x reference)
//
#include <hip/hip_runtime.h>
#include <cstdint>
#include <cstddef>

// ---------------- problem constants ----------------
constexpr int Bn   = 8;
constexpr int Pn   = 2000;
constexpr int Cn   = 81;
constexpr int CM1  = 80;
constexpr int Mn   = Pn * CM1;      // 160000 per image
constexpr int KPRE = 2048;
constexpr int NDET = 100;
constexpr int CAP  = 8192;          // candidate buffer per image (post-threshold)
constexpr int NBINS = 5632;         // score-bits histogram bins
constexpr int BINOFF = (122 << 10); // exponent 122 (scores > 0.05 > 2^-5)
constexpr float W_IMG = 1333.0f;
constexpr float H_IMG = 800.0f;
constexpr float XFORM_CLIP = 4.135166556742356f; // log(1000/16)
constexpr float NMS_OFF = 1334.0f;               // max(W,H)+1

// ---------------- ws layout (bytes) ----------------
// [hist: Bn*NBINS int][cnt: Bn int][T: Bn int]  <- zeroed via hipMemsetAsync
// [scores: Bn*Mn f32][cand: Bn*CAP u64]
// [tscore: Bn*KPRE f32][tbox: Bn*KPRE*4 f32][tlabel: Bn*KPRE int]
// [sup: Bn*KPRE*32 u64]
constexpr size_t OFF_HIST  = 0;
constexpr size_t OFF_CNT   = OFF_HIST + (size_t)Bn * NBINS * 4;
constexpr size_t OFF_T     = OFF_CNT + Bn * 4;
constexpr size_t ZERO_BYTES = OFF_T + Bn * 4;
constexpr size_t OFF_SCORE = ZERO_BYTES;                                  // 5.12 MB
constexpr size_t OFF_CAND  = OFF_SCORE + (size_t)Bn * Mn * 4;
constexpr size_t OFF_TS    = OFF_CAND + (size_t)Bn * CAP * 8;
constexpr size_t OFF_TB    = OFF_TS + (size_t)Bn * KPRE * 4;
constexpr size_t OFF_TL    = OFF_TB + (size_t)Bn * KPRE * 16;
constexpr size_t OFF_SUP   = OFF_TL + (size_t)Bn * KPRE * 4;

__device__ __forceinline__ void decode_clip(const float4 rv, float w, float h,
                                            float cx, float cy, float out[4]) {
  float dx = rv.x / 10.0f;
  float dy = rv.y / 10.0f;
  float dw = fminf(rv.z / 5.0f, XFORM_CLIP);
  float dh = fminf(rv.w / 5.0f, XFORM_CLIP);
  float pcx = dx * w + cx;
  float pcy = dy * h + cy;
  float pw = expf(dw) * w;
  float ph = expf(dh) * h;
  out[0] = fminf(fmaxf(pcx - 0.5f * pw, 0.0f), W_IMG);
  out[1] = fminf(fmaxf(pcy - 0.5f * ph, 0.0f), H_IMG);
  out[2] = fminf(fmaxf(pcx + 0.5f * pw, 0.0f), W_IMG);
  out[3] = fminf(fmaxf(pcy + 0.5f * ph, 0.0f), H_IMG);
}

__device__ __forceinline__ int score_bin(unsigned bits) {
  int bin = (int)(bits >> 13) - BINOFF;
  return min(max(bin, 0), NBINS - 1);
}

// ---------------- K1: softmax + decode + mask + histogram ----------------
__global__ __launch_bounds__(256) void
k1_score(const float* __restrict__ logits, const float* __restrict__ reg,
         const float* __restrict__ props, float* __restrict__ scores,
         int* __restrict__ hist) {
  int wid = blockIdx.x * 4 + (threadIdx.x >> 6);   // proposal id (b*Pn+p)
  int lane = threadIdx.x & 63;
  if (wid >= Bn * Pn) return;
  int b = wid / Pn, p = wid % Pn;

  const float* lg = logits + (size_t)wid * Cn;
  float x0 = lg[lane];
  float x1 = (lane < Cn - 64) ? lg[64 + lane] : -3.4e38f;
  float mx = fmaxf(x0, x1);
  for (int m = 32; m; m >>= 1) mx = fmaxf(mx, __shfl_xor(mx, m, 64));
  float e0 = expf(x0 - mx);
  float e1 = (lane < Cn - 64) ? expf(x1 - mx) : 0.0f;
  float ssum = e0 + e1;
  for (int m = 32; m; m >>= 1) ssum += __shfl_xor(ssum, m, 64);

  const float4 pb = *reinterpret_cast<const float4*>(props + (size_t)wid * 4);
  float w = pb.z - pb.x, h = pb.w - pb.y;
  float cx = pb.x + 0.5f * w, cy = pb.y + 0.5f * h;

  const float* rrow = reg + (size_t)wid * (Cn * 4);
  float* srow = scores + (size_t)b * Mn + (size_t)p * CM1;
  int* hrow = hist + (size_t)b * NBINS;

  #pragma unroll
  for (int slot = 0; slot < 2; slot++) {
    int c = lane + slot * 64;
    float e = slot ? e1 : e0;
    if (c < 1 || c >= Cn) continue;
    float sc = e / ssum;
    float4 rv = *reinterpret_cast<const float4*>(rrow + c * 4);
    float bx[4];
    decode_clip(rv, w, h, cx, cy, bx);
    bool valid = (sc > 0.05f) && (bx[2] - bx[0] >= 0.01f) && (bx[3] - bx[1] >= 0.01f);
    srow[c - 1] = valid ? sc : -1.0f;
    if (valid) atomicAdd(&hrow[score_bin(__float_as_uint(sc))], 1);
  }
}

// ---------------- K2: per-image bin threshold ----------------
__global__ __launch_bounds__(256) void
k2_thresh(const int* __restrict__ hist, int* __restrict__ T) {
  int b = blockIdx.x, t = threadIdx.x;
  __shared__ int partial[256];
  __shared__ int sufAfter[256];
  __shared__ int tmax;
  const int CH = NBINS / 256;  // 22
  const int* hrow = hist + (size_t)b * NBINS;
  int lo = t * CH, hi = lo + CH;
  int s = 0;
  for (int i = lo; i < hi; i++) s += hrow[i];
  partial[t] = s;
  if (t == 0) tmax = 0;
  __syncthreads();
  if (t == 0) {
    int acc = 0;
    for (int q = 255; q >= 0; q--) { sufAfter[q] = acc; acc += partial[q]; }
  }
  __syncthreads();
  int cum = sufAfter[t];
  int cand = -1;
  for (int i = hi - 1; i >= lo; i--) {
    cum += hrow[i];
    if (cum >= KPRE) { cand = i; break; }
  }
  if (cand >= 0) atomicMax(&tmax, cand);
  __syncthreads();
  if (t == 0) T[b] = tmax;
}

// ---------------- K3: compact candidates above threshold ----------------
__global__ __launch_bounds__(256) void
k3_compact(const float* __restrict__ scores, const int* __restrict__ T,
           int* __restrict__ cnt, unsigned long long* __restrict__ cand) {
  int i = blockIdx.x * blockDim.x + threadIdx.x;
  if (i >= Bn * Mn) return;
  float sc = scores[i];
  if (sc <= 0.0f) return;
  int b = i / Mn;
  int m = i - b * Mn;
  unsigned bits = __float_as_uint(sc);
  if (score_bin(bits) < T[b]) return;
  int pos = atomicAdd(&cnt[b], 1);
  if (pos < CAP)
    cand[(size_t)b * CAP + pos] =
        ((unsigned long long)bits << 32) | (unsigned)(0xFFFFFFFFu - (unsigned)m);
}

// ---------------- K4: bitonic sort candidates, emit top-2048 ----------------
__global__ __launch_bounds__(1024) void
k4_sort(const unsigned long long* __restrict__ cand, const int* __restrict__ cnt,
        const float* __restrict__ reg, const float* __restrict__ props,
        float* __restrict__ tscore, float* __restrict__ tbox,
        int* __restrict__ tlabel) {
  __shared__ unsigned long long sk[CAP];  // 64 KB
  int b = blockIdx.x, t = threadIdx.x;
  int n = min(cnt[b], CAP);
  int npow = 2;
  while (npow < n) npow <<= 1;
  for (int i = t; i < npow; i += 1024)
    sk[i] = (i < n) ? cand[(size_t)b * CAP + i] : 0ull;
  __syncthreads();
  for (int k = 2; k <= npow; k <<= 1) {
    for (int j = k >> 1; j > 0; j >>= 1) {
      for (int i = t; i < npow; i += 1024) {
        int ixj = i ^ j;
        if (ixj > i) {
          unsigned long long a = sk[i], c = sk[ixj];
          bool dir = ((i & k) == 0);  // descending overall
          if ((a < c) == dir) { sk[i] = c; sk[ixj] = a; }
        }
      }
      __syncthreads();
    }
  }
  for (int kk = t; kk < KPRE; kk += 1024) {
    float sc = -1.0f, bx[4] = {0.f, 0.f, 0.f, 0.f};
    int label = 0;
    if (kk < n) {
      unsigned long long key = sk[kk];
      sc = __uint_as_float((unsigned)(key >> 32));
      int m = (int)(0xFFFFFFFFu - (unsigned)key);
      int p = m / CM1;
      int c = m - p * CM1 + 1;
      int nidx = b * Pn + p;
      const float4 pb = *reinterpret_cast<const float4*>(props + (size_t)nidx * 4);
      float w = pb.z - pb.x, h = pb.w - pb.y;
      float cx = pb.x + 0.5f * w, cy = pb.y + 0.5f * h;
      float4 rv = *reinterpret_cast<const float4*>(reg + (size_t)nidx * (Cn * 4) + c * 4);
      decode_clip(rv, w, h, cx, cy, bx);
      label = c;
    }
    size_t o = (size_t)b * KPRE + kk;
    tscore[o] = sc;
    tlabel[o] = label;
    tbox[o * 4 + 0] = bx[0]; tbox[o * 4 + 1] = bx[1];
    tbox[o * 4 + 2] = bx[2]; tbox[o * 4 + 3] = bx[3];
  }
}

// ---------------- K5: suppression bitmask (upper triangle) ----------------
__global__ __launch_bounds__(64) void
k5_iou(const float* __restrict__ tbox, const int* __restrict__ tlabel,
       unsigned long long* __restrict__ sup) {
  int b = blockIdx.z, rb = blockIdx.y, cb = blockIdx.x;
  if (cb < rb) return;
  int t = threadIdx.x;
  __shared__ float cbx[64][5];
  int col = cb * 64 + t;
  {
    size_t o = (size_t)b * KPRE + col;
    float off = (float)tlabel[o] * NMS_OFF;
    float4 c4 = *reinterpret_cast<const float4*>(&tbox[o * 4]);
    float x1 = c4.x + off, y1 = c4.y + off, x2 = c4.z + off, y2 = c4.w + off;
    cbx[t][0] = x1; cbx[t][1] = y1; cbx[t][2] = x2; cbx[t][3] = y2;
    cbx[t][4] = fmaxf(x2 - x1, 0.0f) * fmaxf(y2 - y1, 0.0f);
  }
  __syncthreads();
  int row = rb * 64 + t;
  size_t ro = (size_t)b * KPRE + row;
  float off_r = (float)tlabel[ro] * NMS_OFF;
  float4 r4 = *reinterpret_cast<const float4*>(&tbox[ro * 4]);
  float rx1 = r4.x + off_r, ry1 = r4.y + off_r, rx2 = r4.z + off_r, ry2 = r4.w + off_r;
  float area_r = fmaxf(rx2 - rx1, 0.0f) * fmaxf(ry2 - ry1, 0.0f);
  unsigned long long mask = 0;
  #pragma unroll 4
  for (int j = 0; j < 64; j++) {
    int colj = cb * 64 + j;
    float ltx = fmaxf(rx1, cbx[j][0]);
    float lty = fmaxf(ry1, cbx[j][1]);
    float rbx = fminf(rx2, cbx[j][2]);
    float rby = fminf(ry2, cbx[j][3]);
    float iw = fmaxf(rbx - ltx, 0.0f);
    float ih = fmaxf(rby - lty, 0.0f);
    float inter = iw * ih;
    float uni = area_r + cbx[j][4] - inter;
    float iou = inter / fmaxf(uni, 1e-9f);
    if ((iou > 0.5f) && (colj > row)) mask |= (1ull << j);
  }
  sup[ro * 32 + cb] = mask;
}

__device__ __forceinline__ unsigned long long shfl64(unsigned long long v, int src) {
  int lo = __shfl((int)(unsigned)(v & 0xFFFFFFFFull), src, 64);
  int hi = __shfl((int)(unsigned)(v >> 32), src, 64);
  return ((unsigned long long)(unsigned)hi << 32) | (unsigned)(unsigned)lo;
}

// ---------------- K6: sequential greedy NMS + top-100 + output ----------------
__global__ __launch_bounds__(64) void
k6_nms(const float* __restrict__ tscore, const float* __restrict__ tbox,
       const int* __restrict__ tlabel, const unsigned long long* __restrict__ sup,
       float* __restrict__ out) {
  int b = blockIdx.x, lane = threadIdx.x;
  // init keep = valid bits (score > 0); word w lives in lane w (w<32)
  unsigned long long keep = 0;
  for (int w = 0; w < 32; w++) {
    float sc = tscore[(size_t)b * KPRE + w * 64 + lane];
    unsigned long long bal = __ballot(sc > 0.0f);
    if (lane == w) keep = bal;
  }
  const unsigned long long* srow = sup + (size_t)b * KPRE * 32;
  int wt = lane & 31;
  unsigned long long pf[4];
  #pragma unroll
  for (int d = 0; d < 4; d++) pf[d] = srow[(size_t)d * 32 + wt];
  for (int i0 = 0; i0 < KPRE; i0 += 4) {
    #pragma unroll
    for (int d = 0; d < 4; d++) {
      int i = i0 + d;
      unsigned long long cur = pf[d];
      int nx = i + 4;
      pf[d] = (nx < KPRE) ? srow[(size_t)nx * 32 + wt] : 0ull;
      int wi = i >> 6;
      unsigned long long kv = shfl64(keep, wi);
      if (((kv >> (i & 63)) & 1ull) && (wt >= wi)) keep &= ~cur;
    }
  }
  // stable top-100: kept positions ascending, then non-kept ascending
  __shared__ int detk[NDET];
  unsigned long long kw = (lane < 32) ? keep : 0ull;
  int pc = __popcll(kw);
  int incl = pc;
  for (int s = 1; s < 64; s <<= 1) {
    int y = __shfl_up(incl, s, 64);
    if (lane >= s) incl += y;
  }
  int excl = incl - pc;
  int total = __shfl(incl, 63, 64);
  {
    int running = excl;
    for (int bit = 0; bit < 64; bit++) {
      if ((kw >> bit) & 1ull) {
        if (running < NDET) detk[running] = lane * 64 + bit;
        running++;
      }
    }
  }
  if (total < NDET) {
    unsigned long long nk = (lane < 32) ? ~keep : 0ull;
    int pcn = __popcll(nk);
    int incn = pcn;
    for (int s = 1; s < 64; s <<= 1) {
      int y = __shfl_up(incn, s, 64);
      if (lane >= s) incn += y;
    }
    int excn = incn - pcn;
    int running = total + excn;
    for (int bit = 0; bit < 64; bit++) {
      if ((nk >> bit) & 1ull) {
        if (running >= 0 && running < NDET) detk[running] = lane * 64 + bit;
        running++;
      }
    }
  }
  __syncthreads();
  for (int s = lane; s < NDET; s += 64) {
    int k = detk[s];
    bool kept = (s < total);
    size_t o = (size_t)b * KPRE + k;
    float sc = kept ? tscore[o] : -1.0f;
    float4 bx = *reinterpret_cast<const float4*>(&tbox[o * 4]);
    int lb = tlabel[o];
    int oi = b * NDET + s;
    out[(size_t)oi * 4 + 0] = bx.x;
    out[(size_t)oi * 4 + 1] = bx.y;
    out[(size_t)oi * 4 + 2] = bx.z;
    out[(size_t)oi * 4 + 3] = bx.w;
    out[Bn * NDET * 4 + oi] = sc;
    out[Bn * NDET * 5 + oi] = (float)lb;
    out[Bn * NDET * 6 + oi] = kept ? 1.0f : 0.0f;
  }
}

extern "C" void kernel_launch(void* const* d_in, const int* in_sizes, int n_in,
                              void* d_out, int out_size, void* d_ws, size_t ws_size,
                              hipStream_t stream) {
  const float* logits = (const float*)d_in[0];
  const float* reg    = (const float*)d_in[1];
  const float* props  = (const float*)d_in[2];
  float* out = (float*)d_out;
  char* ws = (char*)d_ws;

  int*   hist   = (int*)(ws + OFF_HIST);
  int*   cnt    = (int*)(ws + OFF_CNT);
  int*   T      = (int*)(ws + OFF_T);
  float* scores = (float*)(ws + OFF_SCORE);
  unsigned long long* cand = (unsigned long long*)(ws + OFF_CAND);
  float* tscore = (float*)(ws + OFF_TS);
  float* tbox   = (float*)(ws + OFF_TB);
  int*   tlabel = (int*)(ws + OFF_TL);
  unsigned long long* sup = (unsigned long long*)(ws + OFF_SUP);

  hipMemsetAsync(ws, 0, ZERO_BYTES, stream);
  k1_score<<<(Bn * Pn) / 4, 256, 0, stream>>>(logits, reg, props, scores, hist);
  k2_thresh<<<Bn, 256, 0, stream>>>(hist, T);
  k3_compact<<<(Bn * Mn) / 256, 256, 0, stream>>>(scores, T, cnt, cand);
  k4_sort<<<Bn, 1024, 0, stream>>>(cand, cnt, reg, props, tscore, tbox, tlabel);
  k5_iou<<<dim3(KPRE / 64, KPRE / 64, Bn), 64, 0, stream>>>(tbox, tlabel, sup);
  k6_nms<<<Bn, 64, 0, stream>>>(tscore, tbox, tlabel, sup, out);
}

// Round 2
// 231.252 us; speedup vs baseline: 3.7153x; 3.7153x over previous
//
#include <hip/hip_runtime.h>
#include <cstdint>
#include <cstddef>

// ---------------- problem constants ----------------
constexpr int Bn   = 8;
constexpr int Pn   = 2000;
constexpr int Cn   = 81;
constexpr int CM1  = 80;
constexpr int Mn   = Pn * CM1;      // 160000 per image
constexpr int KPRE = 2048;
constexpr int NDET = 100;
constexpr int CAP  = 8192;          // candidate buffer per image (post-threshold)
constexpr int NBINS = 5632;         // score-bits histogram bins
constexpr int BINOFF = (122 << 10); // exponent 122 (scores > 0.05 > 2^-5)
constexpr int BPI  = Mn / 256;      // 625 blocks per image in k3 passes
constexpr float W_IMG = 1333.0f;
constexpr float H_IMG = 800.0f;
constexpr float XFORM_CLIP = 4.135166556742356f; // log(1000/16)
constexpr float NMS_OFF = 1334.0f;               // max(W,H)+1

// ---------------- ws layout (bytes) ----------------
constexpr size_t OFF_HIST  = 0;                                   // memset to 0
constexpr size_t ZERO_BYTES = (size_t)Bn * NBINS * 4;             // 180224
constexpr size_t OFF_CNT   = ZERO_BYTES;                          // Bn int (written by k3b)
constexpr size_t OFF_T     = OFF_CNT + Bn * 4;                    // Bn int (written by k2)
constexpr size_t OFF_BC    = OFF_T + Bn * 4;                      // Bn*BPI int
constexpr size_t OFF_BO    = OFF_BC + (size_t)Bn * BPI * 4;       // Bn*BPI int
constexpr size_t OFF_SCORE = OFF_BO + (size_t)Bn * BPI * 4;       // Bn*Mn f32 (5.12 MB)
constexpr size_t OFF_CAND  = OFF_SCORE + (size_t)Bn * Mn * 4;     // Bn*CAP u64
constexpr size_t OFF_TS    = OFF_CAND + (size_t)Bn * CAP * 8;     // Bn*KPRE f32
constexpr size_t OFF_TB    = OFF_TS + (size_t)Bn * KPRE * 4;      // Bn*KPRE*4 f32
constexpr size_t OFF_TL    = OFF_TB + (size_t)Bn * KPRE * 16;     // Bn*KPRE int

__device__ __forceinline__ void decode_clip(const float4 rv, float w, float h,
                                            float cx, float cy, float out[4]) {
  float dx = rv.x / 10.0f;
  float dy = rv.y / 10.0f;
  float dw = fminf(rv.z / 5.0f, XFORM_CLIP);
  float dh = fminf(rv.w / 5.0f, XFORM_CLIP);
  float pcx = dx * w + cx;
  float pcy = dy * h + cy;
  float pw = expf(dw) * w;
  float ph = expf(dh) * h;
  out[0] = fminf(fmaxf(pcx - 0.5f * pw, 0.0f), W_IMG);
  out[1] = fminf(fmaxf(pcy - 0.5f * ph, 0.0f), H_IMG);
  out[2] = fminf(fmaxf(pcx + 0.5f * pw, 0.0f), W_IMG);
  out[3] = fminf(fmaxf(pcy + 0.5f * ph, 0.0f), H_IMG);
}

__device__ __forceinline__ int score_bin(unsigned bits) {
  int bin = (int)(bits >> 13) - BINOFF;
  return min(max(bin, 0), NBINS - 1);
}

// ---------------- K1: softmax + decode + mask + histogram ----------------
__global__ __launch_bounds__(256) void
k1_score(const float* __restrict__ logits, const float* __restrict__ reg,
         const float* __restrict__ props, float* __restrict__ scores,
         int* __restrict__ hist) {
  int wid = blockIdx.x * 4 + (threadIdx.x >> 6);   // proposal id (b*Pn+p)
  int lane = threadIdx.x & 63;
  if (wid >= Bn * Pn) return;
  int b = wid / Pn, p = wid % Pn;

  const float* lg = logits + (size_t)wid * Cn;
  float x0 = lg[lane];
  float x1 = (lane < Cn - 64) ? lg[64 + lane] : -3.4e38f;
  float mx = fmaxf(x0, x1);
  for (int m = 32; m; m >>= 1) mx = fmaxf(mx, __shfl_xor(mx, m, 64));
  float e0 = expf(x0 - mx);
  float e1 = (lane < Cn - 64) ? expf(x1 - mx) : 0.0f;
  float ssum = e0 + e1;
  for (int m = 32; m; m >>= 1) ssum += __shfl_xor(ssum, m, 64);

  const float4 pb = *reinterpret_cast<const float4*>(props + (size_t)wid * 4);
  float w = pb.z - pb.x, h = pb.w - pb.y;
  float cx = pb.x + 0.5f * w, cy = pb.y + 0.5f * h;

  const float* rrow = reg + (size_t)wid * (Cn * 4);
  float* srow = scores + (size_t)b * Mn + (size_t)p * CM1;
  int* hrow = hist + (size_t)b * NBINS;

  #pragma unroll
  for (int slot = 0; slot < 2; slot++) {
    int c = lane + slot * 64;
    float e = slot ? e1 : e0;
    if (c < 1 || c >= Cn) continue;
    float sc = e / ssum;
    float4 rv = *reinterpret_cast<const float4*>(rrow + c * 4);
    float bx[4];
    decode_clip(rv, w, h, cx, cy, bx);
    bool valid = (sc > 0.05f) && (bx[2] - bx[0] >= 0.01f) && (bx[3] - bx[1] >= 0.01f);
    srow[c - 1] = valid ? sc : -1.0f;
    if (valid) atomicAdd(&hrow[score_bin(__float_as_uint(sc))], 1);
  }
}

// ---------------- K2: per-image bin threshold ----------------
__global__ __launch_bounds__(256) void
k2_thresh(const int* __restrict__ hist, int* __restrict__ T) {
  int b = blockIdx.x, t = threadIdx.x;
  __shared__ int partial[256];
  __shared__ int sufAfter[256];
  __shared__ int tmax;
  const int CH = NBINS / 256;  // 22
  const int* hrow = hist + (size_t)b * NBINS;
  int lo = t * CH, hi = lo + CH;
  int s = 0;
  for (int i = lo; i < hi; i++) s += hrow[i];
  partial[t] = s;
  if (t == 0) tmax = 0;
  __syncthreads();
  if (t == 0) {
    int acc = 0;
    for (int q = 255; q >= 0; q--) { sufAfter[q] = acc; acc += partial[q]; }
  }
  __syncthreads();
  int cum = sufAfter[t];
  int cand = -1;
  for (int i = hi - 1; i >= lo; i--) {
    cum += hrow[i];
    if (cum >= KPRE) { cand = i; break; }
  }
  if (cand >= 0) atomicMax(&tmax, cand);
  __syncthreads();
  if (t == 0) T[b] = tmax;
}

// ---------------- K3a: per-block candidate count (no atomics) ----------------
__global__ __launch_bounds__(256) void
k3a_count(const float* __restrict__ scores, const int* __restrict__ T,
          int* __restrict__ bcount) {
  int blk = blockIdx.x, t = threadIdx.x;
  int i = blk * 256 + t;
  int b = blk / BPI;
  float sc = scores[i];
  bool pass = (sc > 0.0f) && (score_bin(__float_as_uint(sc)) >= T[b]);
  unsigned long long bal = __ballot(pass);
  __shared__ int wc[4];
  if ((t & 63) == 0) wc[t >> 6] = __popcll(bal);
  __syncthreads();
  if (t == 0) bcount[blk] = wc[0] + wc[1] + wc[2] + wc[3];
}

// ---------------- K3b: per-image exclusive scan of block counts ----------------
__global__ __launch_bounds__(256) void
k3b_scan(const int* __restrict__ bcount, int* __restrict__ boffs,
         int* __restrict__ cnt) {
  int b = blockIdx.x, t = threadIdx.x;
  int lane = t & 63, w = t >> 6;
  int base = b * BPI;
  int i0 = t * 3;  // 256*3 = 768 >= 625
  int v0 = (i0     < BPI) ? bcount[base + i0]     : 0;
  int v1 = (i0 + 1 < BPI) ? bcount[base + i0 + 1] : 0;
  int v2 = (i0 + 2 < BPI) ? bcount[base + i0 + 2] : 0;
  int tsum = v0 + v1 + v2;
  int incl = tsum;
  for (int s = 1; s < 64; s <<= 1) {
    int y = __shfl_up(incl, s, 64);
    if (lane >= s) incl += y;
  }
  __shared__ int wsum[4];
  if (lane == 63) wsum[w] = incl;
  __syncthreads();
  int woff = 0;
  for (int q = 0; q < w; q++) woff += wsum[q];
  int excl = woff + incl - tsum;
  if (i0     < BPI) boffs[base + i0]     = excl;
  if (i0 + 1 < BPI) boffs[base + i0 + 1] = excl + v0;
  if (i0 + 2 < BPI) boffs[base + i0 + 2] = excl + v0 + v1;
  if (t == 255) cnt[b] = excl + tsum;  // image total
}

// ---------------- K3c: scatter at scanned offsets ----------------
__global__ __launch_bounds__(256) void
k3c_scatter(const float* __restrict__ scores, const int* __restrict__ T,
            const int* __restrict__ boffs, unsigned long long* __restrict__ cand) {
  int blk = blockIdx.x, t = threadIdx.x, lane = t & 63, w = t >> 6;
  int i = blk * 256 + t;
  int b = blk / BPI;
  int m = i - b * Mn;
  float sc = scores[i];
  unsigned bits = __float_as_uint(sc);
  bool pass = (sc > 0.0f) && (score_bin(bits) >= T[b]);
  unsigned long long bal = __ballot(pass);
  __shared__ int wc[4];
  if (lane == 0) wc[w] = __popcll(bal);
  __syncthreads();
  int base = boffs[blk];
  for (int q = 0; q < w; q++) base += wc[q];
  int rank = __popcll(bal & ((1ull << lane) - 1ull));
  int pos = base + rank;
  if (pass && pos < CAP)
    cand[(size_t)b * CAP + pos] =
        ((unsigned long long)bits << 32) | (unsigned)(0xFFFFFFFFu - (unsigned)m);
}

// ---------------- K4: bitonic sort candidates, emit top-2048 ----------------
__global__ __launch_bounds__(1024) void
k4_sort(const unsigned long long* __restrict__ cand, const int* __restrict__ cnt,
        const float* __restrict__ reg, const float* __restrict__ props,
        float* __restrict__ tscore, float* __restrict__ tbox,
        int* __restrict__ tlabel) {
  __shared__ unsigned long long sk[CAP];  // 64 KB
  int b = blockIdx.x, t = threadIdx.x;
  int n = min(cnt[b], CAP);
  int npow = 2;
  while (npow < n) npow <<= 1;
  for (int i = t; i < npow; i += 1024)
    sk[i] = (i < n) ? cand[(size_t)b * CAP + i] : 0ull;
  __syncthreads();
  for (int k = 2; k <= npow; k <<= 1) {
    for (int j = k >> 1; j > 0; j >>= 1) {
      for (int i = t; i < npow; i += 1024) {
        int ixj = i ^ j;
        if (ixj > i) {
          unsigned long long a = sk[i], c = sk[ixj];
          bool dir = ((i & k) == 0);  // descending overall
          if ((a < c) == dir) { sk[i] = c; sk[ixj] = a; }
        }
      }
      __syncthreads();
    }
  }
  for (int kk = t; kk < KPRE; kk += 1024) {
    float sc = -1.0f, bx[4] = {0.f, 0.f, 0.f, 0.f};
    int label = 0;
    if (kk < n) {
      unsigned long long key = sk[kk];
      sc = __uint_as_float((unsigned)(key >> 32));
      int m = (int)(0xFFFFFFFFu - (unsigned)key);
      int p = m / CM1;
      int c = m - p * CM1 + 1;
      int nidx = b * Pn + p;
      const float4 pb = *reinterpret_cast<const float4*>(props + (size_t)nidx * 4);
      float w = pb.z - pb.x, h = pb.w - pb.y;
      float cx = pb.x + 0.5f * w, cy = pb.y + 0.5f * h;
      float4 rv = *reinterpret_cast<const float4*>(reg + (size_t)nidx * (Cn * 4) + c * 4);
      decode_clip(rv, w, h, cx, cy, bx);
      label = c;
    }
    size_t o = (size_t)b * KPRE + kk;
    tscore[o] = sc;
    tlabel[o] = label;
    tbox[o * 4 + 0] = bx[0]; tbox[o * 4 + 1] = bx[1];
    tbox[o * 4 + 2] = bx[2]; tbox[o * 4 + 3] = bx[3];
  }
}

// ---------------- K5: fused greedy NMS with early exit + output ----------------
// One 1024-thread block per image. Boxes in LDS (SoA, 40 KB). Keep mask =
// 32 x u64 in LDS, updated via per-wave ballot (wave w owns words w and 16+w).
// Greedy decisions are prefix-correct -> stop once 100 boxes kept.
__global__ __launch_bounds__(1024) void
k5_nms(const float* __restrict__ tscore, const float* __restrict__ tbox,
       const int* __restrict__ tlabel, float* __restrict__ out) {
  int b = blockIdx.x, t = threadIdx.x, lane = t & 63, w = t >> 6;
  __shared__ float sx1[KPRE], sy1[KPRE], sx2[KPRE], sy2[KPRE], sar[KPRE];
  __shared__ unsigned long long keepw[KPRE / 64];  // 32 words
  __shared__ int detk[NDET];

  #pragma unroll
  for (int s = 0; s < 2; s++) {
    int j = t + s * 1024;
    size_t o = (size_t)b * KPRE + j;
    float4 bx = *reinterpret_cast<const float4*>(&tbox[o * 4]);
    float off = (float)tlabel[o] * NMS_OFF;
    float x1 = bx.x + off, y1 = bx.y + off, x2 = bx.z + off, y2 = bx.w + off;
    sx1[j] = x1; sy1[j] = y1; sx2[j] = x2; sy2[j] = y2;
    sar[j] = fmaxf(x2 - x1, 0.0f) * fmaxf(y2 - y1, 0.0f);
    unsigned long long bal = __ballot(tscore[o] > 0.0f);
    if (lane == 0) keepw[s * 16 + w] = bal;
  }
  __syncthreads();

  int kcount = 0;
  int i = 0;
  while (i < KPRE && kcount < NDET) {
    int wi = i >> 6;
    unsigned long long word = keepw[wi];                  // uniform broadcast read
    unsigned long long rem = word & (~0ull << (i & 63));
    while (rem) {
      int bit = __ffsll((long long)rem) - 1;
      int ii = wi * 64 + bit;                             // accepted (kept) box
      if (t == 0) detk[kcount] = ii;
      kcount++;
      if (kcount >= NDET) break;
      float ax1 = sx1[ii], ay1 = sy1[ii], ax2 = sx2[ii], ay2 = sy2[ii];
      float aar = sar[ii];
      unsigned long long bb[2];
      #pragma unroll
      for (int s = 0; s < 2; s++) {
        int j = t + s * 1024;
        float ix1 = fmaxf(ax1, sx1[j]);
        float iy1 = fmaxf(ay1, sy1[j]);
        float ix2 = fminf(ax2, sx2[j]);
        float iy2 = fminf(ay2, sy2[j]);
        float iw = fmaxf(ix2 - ix1, 0.0f);
        float ih = fmaxf(iy2 - iy1, 0.0f);
        float inter = iw * ih;
        float uni = aar + sar[j] - inter;
        bool sup = (j > ii) && (inter / fmaxf(uni, 1e-9f) > 0.5f);
        bb[s] = __ballot(sup);
      }
      if (lane == 0) {
        keepw[w]      &= ~bb[0];
        keepw[16 + w] &= ~bb[1];
      }
      __syncthreads();
      word = keepw[wi];
      rem = (bit == 63) ? 0ull : (word & (~0ull << (bit + 1)));
    }
    i = (wi + 1) << 6;
  }
  __syncthreads();

  // rare path: fewer than 100 kept -> backfill with non-kept positions ascending
  if (t == 0 && kcount < NDET) {
    int run = kcount;
    for (int wq = 0; wq < KPRE / 64 && run < NDET; wq++) {
      unsigned long long nk = ~keepw[wq];
      while (nk && run < NDET) {
        int bit2 = __ffsll((long long)nk) - 1;
        nk &= nk - 1;
        detk[run++] = wq * 64 + bit2;
      }
    }
  }
  __syncthreads();

  if (t < NDET) {
    int k = detk[t];
    bool kept = t < kcount;
    size_t o = (size_t)b * KPRE + k;
    float4 bx = *reinterpret_cast<const float4*>(&tbox[o * 4]);
    int oi = b * NDET + t;
    out[(size_t)oi * 4 + 0] = bx.x;
    out[(size_t)oi * 4 + 1] = bx.y;
    out[(size_t)oi * 4 + 2] = bx.z;
    out[(size_t)oi * 4 + 3] = bx.w;
    out[Bn * NDET * 4 + oi] = kept ? tscore[o] : -1.0f;
    out[Bn * NDET * 5 + oi] = (float)tlabel[o];
    out[Bn * NDET * 6 + oi] = kept ? 1.0f : 0.0f;
  }
}

extern "C" void kernel_launch(void* const* d_in, const int* in_sizes, int n_in,
                              void* d_out, int out_size, void* d_ws, size_t ws_size,
                              hipStream_t stream) {
  const float* logits = (const float*)d_in[0];
  const float* reg    = (const float*)d_in[1];
  const float* props  = (const float*)d_in[2];
  float* out = (float*)d_out;
  char* ws = (char*)d_ws;

  int*   hist   = (int*)(ws + OFF_HIST);
  int*   cnt    = (int*)(ws + OFF_CNT);
  int*   T      = (int*)(ws + OFF_T);
  int*   bcount = (int*)(ws + OFF_BC);
  int*   boffs  = (int*)(ws + OFF_BO);
  float* scores = (float*)(ws + OFF_SCORE);
  unsigned long long* cand = (unsigned long long*)(ws + OFF_CAND);
  float* tscore = (float*)(ws + OFF_TS);
  float* tbox   = (float*)(ws + OFF_TB);
  int*   tlabel = (int*)(ws + OFF_TL);

  hipMemsetAsync(ws + OFF_HIST, 0, ZERO_BYTES, stream);
  k1_score<<<(Bn * Pn) / 4, 256, 0, stream>>>(logits, reg, props, scores, hist);
  k2_thresh<<<Bn, 256, 0, stream>>>(hist, T);
  k3a_count<<<Bn * BPI, 256, 0, stream>>>(scores, T, bcount);
  k3b_scan<<<Bn, 256, 0, stream>>>(bcount, boffs, cnt);
  k3c_scatter<<<Bn * BPI, 256, 0, stream>>>(scores, T, boffs, cand);
  k4_sort<<<Bn, 1024, 0, stream>>>(cand, cnt, reg, props, tscore, tbox, tlabel);
  k5_nms<<<Bn, 1024, 0, stream>>>(tscore, tbox, tlabel, out);
}

// Round 3
// 176.454 us; speedup vs baseline: 4.8691x; 1.3106x over previous
//
#include <hip/hip_runtime.h>
#include <cstdint>
#include <cstddef>

// ---------------- problem constants ----------------
constexpr int Bn   = 8;
constexpr int Pn   = 2000;
constexpr int Cn   = 81;
constexpr int CM1  = 80;
constexpr int Mn   = Pn * CM1;      // 160000 per image
constexpr int KPRE = 2048;
constexpr int NDET = 100;
constexpr int CAP  = 8192;          // candidate buffer per image (post-threshold)
constexpr int NBINS = 5632;         // score-bits histogram bins
constexpr int BINOFF = (122 << 10); // exponent 122 (scores > 0.05 > 2^-5)
constexpr int BPI  = Mn / 256;      // 625 blocks per image in k3 passes
constexpr int WCOLS = 256;          // NMS window size
constexpr float W_IMG = 1333.0f;
constexpr float H_IMG = 800.0f;
constexpr float XFORM_CLIP = 4.135166556742356f; // log(1000/16)
constexpr float NMS_OFF = 1334.0f;               // max(W,H)+1

// ---------------- ws layout (bytes) ----------------
constexpr size_t OFF_HIST  = 0;                                   // memset to 0
constexpr size_t ZERO_BYTES = (size_t)Bn * NBINS * 4;             // 180224
constexpr size_t OFF_CNT   = ZERO_BYTES;                          // Bn int
constexpr size_t OFF_T     = OFF_CNT + Bn * 4;                    // Bn int
constexpr size_t OFF_BC    = OFF_T + Bn * 4;                      // Bn*BPI int
constexpr size_t OFF_BO    = OFF_BC + (size_t)Bn * BPI * 4;       // Bn*BPI int
constexpr size_t OFF_SCORE = OFF_BO + (size_t)Bn * BPI * 4;       // Bn*Mn f32 (5.12 MB)
constexpr size_t OFF_CAND  = OFF_SCORE + (size_t)Bn * Mn * 4;     // Bn*CAP u64

__device__ __forceinline__ void decode_clip(const float4 rv, float w, float h,
                                            float cx, float cy, float out[4]) {
  float dx = rv.x / 10.0f;
  float dy = rv.y / 10.0f;
  float dw = fminf(rv.z / 5.0f, XFORM_CLIP);
  float dh = fminf(rv.w / 5.0f, XFORM_CLIP);
  float pcx = dx * w + cx;
  float pcy = dy * h + cy;
  float pw = expf(dw) * w;
  float ph = expf(dh) * h;
  out[0] = fminf(fmaxf(pcx - 0.5f * pw, 0.0f), W_IMG);
  out[1] = fminf(fmaxf(pcy - 0.5f * ph, 0.0f), H_IMG);
  out[2] = fminf(fmaxf(pcx + 0.5f * pw, 0.0f), W_IMG);
  out[3] = fminf(fmaxf(pcy + 0.5f * ph, 0.0f), H_IMG);
}

__device__ __forceinline__ int score_bin(unsigned bits) {
  int bin = (int)(bits >> 13) - BINOFF;
  return min(max(bin, 0), NBINS - 1);
}

// ---------------- K1: softmax + decode + mask + histogram ----------------
__global__ __launch_bounds__(256) void
k1_score(const float* __restrict__ logits, const float* __restrict__ reg,
         const float* __restrict__ props, float* __restrict__ scores,
         int* __restrict__ hist) {
  int wid = blockIdx.x * 4 + (threadIdx.x >> 6);   // proposal id (b*Pn+p)
  int lane = threadIdx.x & 63;
  if (wid >= Bn * Pn) return;
  int b = wid / Pn, p = wid % Pn;

  const float* lg = logits + (size_t)wid * Cn;
  float x0 = lg[lane];
  float x1 = (lane < Cn - 64) ? lg[64 + lane] : -3.4e38f;
  float mx = fmaxf(x0, x1);
  for (int m = 32; m; m >>= 1) mx = fmaxf(mx, __shfl_xor(mx, m, 64));
  float e0 = expf(x0 - mx);
  float e1 = (lane < Cn - 64) ? expf(x1 - mx) : 0.0f;
  float ssum = e0 + e1;
  for (int m = 32; m; m >>= 1) ssum += __shfl_xor(ssum, m, 64);

  const float4 pb = *reinterpret_cast<const float4*>(props + (size_t)wid * 4);
  float w = pb.z - pb.x, h = pb.w - pb.y;
  float cx = pb.x + 0.5f * w, cy = pb.y + 0.5f * h;

  const float* rrow = reg + (size_t)wid * (Cn * 4);
  float* srow = scores + (size_t)b * Mn + (size_t)p * CM1;
  int* hrow = hist + (size_t)b * NBINS;

  #pragma unroll
  for (int slot = 0; slot < 2; slot++) {
    int c = lane + slot * 64;
    float e = slot ? e1 : e0;
    if (c < 1 || c >= Cn) continue;
    float sc = e / ssum;
    float4 rv = *reinterpret_cast<const float4*>(rrow + c * 4);
    float bx[4];
    decode_clip(rv, w, h, cx, cy, bx);
    bool valid = (sc > 0.05f) && (bx[2] - bx[0] >= 0.01f) && (bx[3] - bx[1] >= 0.01f);
    srow[c - 1] = valid ? sc : -1.0f;
    if (valid) atomicAdd(&hrow[score_bin(__float_as_uint(sc))], 1);
  }
}

// ---------------- K2: per-image bin threshold ----------------
__global__ __launch_bounds__(256) void
k2_thresh(const int* __restrict__ hist, int* __restrict__ T) {
  int b = blockIdx.x, t = threadIdx.x;
  __shared__ int partial[256];
  __shared__ int sufAfter[256];
  __shared__ int tmax;
  const int CH = NBINS / 256;  // 22
  const int* hrow = hist + (size_t)b * NBINS;
  int lo = t * CH, hi = lo + CH;
  int s = 0;
  for (int i = lo; i < hi; i++) s += hrow[i];
  partial[t] = s;
  if (t == 0) tmax = 0;
  __syncthreads();
  if (t == 0) {
    int acc = 0;
    for (int q = 255; q >= 0; q--) { sufAfter[q] = acc; acc += partial[q]; }
  }
  __syncthreads();
  int cum = sufAfter[t];
  int cand = -1;
  for (int i = hi - 1; i >= lo; i--) {
    cum += hrow[i];
    if (cum >= KPRE) { cand = i; break; }
  }
  if (cand >= 0) atomicMax(&tmax, cand);
  __syncthreads();
  if (t == 0) T[b] = tmax;
}

// ---------------- K3a: per-block candidate count (no atomics) ----------------
__global__ __launch_bounds__(256) void
k3a_count(const float* __restrict__ scores, const int* __restrict__ T,
          int* __restrict__ bcount) {
  int blk = blockIdx.x, t = threadIdx.x;
  int i = blk * 256 + t;
  int b = blk / BPI;
  float sc = scores[i];
  bool pass = (sc > 0.0f) && (score_bin(__float_as_uint(sc)) >= T[b]);
  unsigned long long bal = __ballot(pass);
  __shared__ int wc[4];
  if ((t & 63) == 0) wc[t >> 6] = __popcll(bal);
  __syncthreads();
  if (t == 0) bcount[blk] = wc[0] + wc[1] + wc[2] + wc[3];
}

// ---------------- K3b: per-image exclusive scan of block counts ----------------
__global__ __launch_bounds__(256) void
k3b_scan(const int* __restrict__ bcount, int* __restrict__ boffs,
         int* __restrict__ cnt) {
  int b = blockIdx.x, t = threadIdx.x;
  int lane = t & 63, w = t >> 6;
  int base = b * BPI;
  int i0 = t * 3;  // 256*3 = 768 >= 625
  int v0 = (i0     < BPI) ? bcount[base + i0]     : 0;
  int v1 = (i0 + 1 < BPI) ? bcount[base + i0 + 1] : 0;
  int v2 = (i0 + 2 < BPI) ? bcount[base + i0 + 2] : 0;
  int tsum = v0 + v1 + v2;
  int incl = tsum;
  for (int s = 1; s < 64; s <<= 1) {
    int y = __shfl_up(incl, s, 64);
    if (lane >= s) incl += y;
  }
  __shared__ int wsum[4];
  if (lane == 63) wsum[w] = incl;
  __syncthreads();
  int woff = 0;
  for (int q = 0; q < w; q++) woff += wsum[q];
  int excl = woff + incl - tsum;
  if (i0     < BPI) boffs[base + i0]     = excl;
  if (i0 + 1 < BPI) boffs[base + i0 + 1] = excl + v0;
  if (i0 + 2 < BPI) boffs[base + i0 + 2] = excl + v0 + v1;
  if (t == 255) cnt[b] = excl + tsum;  // image total
}

// ---------------- K3c: scatter at scanned offsets ----------------
__global__ __launch_bounds__(256) void
k3c_scatter(const float* __restrict__ scores, const int* __restrict__ T,
            const int* __restrict__ boffs, unsigned long long* __restrict__ cand) {
  int blk = blockIdx.x, t = threadIdx.x, lane = t & 63, w = t >> 6;
  int i = blk * 256 + t;
  int b = blk / BPI;
  int m = i - b * Mn;
  float sc = scores[i];
  unsigned bits = __float_as_uint(sc);
  bool pass = (sc > 0.0f) && (score_bin(bits) >= T[b]);
  unsigned long long bal = __ballot(pass);
  __shared__ int wc[4];
  if (lane == 0) wc[w] = __popcll(bal);
  __syncthreads();
  int base = boffs[blk];
  for (int q = 0; q < w; q++) base += wc[q];
  int rank = __popcll(bal & ((1ull << lane) - 1ull));
  int pos = base + rank;
  if (pass && pos < CAP)
    cand[(size_t)b * CAP + pos] =
        ((unsigned long long)bits << 32) | (unsigned)(0xFFFFFFFFu - (unsigned)m);
}

// ---------------- K4: bitonic sort candidates, write sorted keys back ----------------
__global__ __launch_bounds__(1024) void
k4_sort(unsigned long long* __restrict__ cand, const int* __restrict__ cnt) {
  __shared__ unsigned long long sk[CAP];  // 64 KB
  int b = blockIdx.x, t = threadIdx.x;
  int n = min(cnt[b], CAP);
  int npow = 2;
  while (npow < n) npow <<= 1;
  for (int i = t; i < npow; i += 1024)
    sk[i] = (i < n) ? cand[(size_t)b * CAP + i] : 0ull;
  __syncthreads();
  for (int k = 2; k <= npow; k <<= 1) {
    for (int j = k >> 1; j > 0; j >>= 1) {
      for (int i = t; i < npow; i += 1024) {
        int ixj = i ^ j;
        if (ixj > i) {
          unsigned long long a = sk[i], c = sk[ixj];
          bool dir = ((i & k) == 0);  // descending overall
          if ((a < c) == dir) { sk[i] = c; sk[ixj] = a; }
        }
      }
      __syncthreads();
    }
  }
  // write first KPRE sorted keys back (zero-pad if fewer)
  for (int kk = t; kk < KPRE; kk += 1024)
    cand[(size_t)b * CAP + kk] = (kk < npow) ? sk[kk] : 0ull;
}

// decode a candidate key into raw clipped box + label + score
__device__ __forceinline__ void key_decode(unsigned long long key, int b,
                                           const float* __restrict__ reg,
                                           const float* __restrict__ props,
                                           float bx[4], int& label, float& sc) {
  sc = __uint_as_float((unsigned)(key >> 32));
  bx[0] = bx[1] = bx[2] = bx[3] = 0.0f;
  label = 0;
  if (key != 0ull) {
    int m = (int)(0xFFFFFFFFu - (unsigned)key);
    int p = m / CM1;
    int c = m - p * CM1 + 1;
    int nidx = b * Pn + p;
    const float4 pb = *reinterpret_cast<const float4*>(props + (size_t)nidx * 4);
    float w = pb.z - pb.x, h = pb.w - pb.y;
    float cx = pb.x + 0.5f * w, cy = pb.y + 0.5f * h;
    float4 rv = *reinterpret_cast<const float4*>(reg + (size_t)nidx * (Cn * 4) + c * 4);
    decode_clip(rv, w, h, cx, cy, bx);
    label = c;
  }
}

// ---------------- K5: windowed bitmask NMS + output ----------------
// One 1024-thread block per image. Per 256-col window:
//   step1: pre-suppress cols vs accepted list (parallel, no divergence cost)
//   step2: 256x256 suppression bitmask, each thread emits one u64 word
//   step3: single-wave serial reduce, keep-words in registers
// Early-exit once 100 kept (greedy decisions are prefix-correct).
__global__ __launch_bounds__(1024) void
k5_nms(const unsigned long long* __restrict__ cand,
       const float* __restrict__ reg, const float* __restrict__ props,
       float* __restrict__ out) {
  int b = blockIdx.x, t = threadIdx.x, lane = t & 63, w = t >> 6;
  __shared__ float4 obox[KPRE];                    // offset boxes, 32 KB
  __shared__ float  sar[KPRE];                     // areas, 8 KB
  __shared__ unsigned long long mask[WCOLS][4];    // 8 KB
  __shared__ unsigned long long keepw[KPRE / 64];  // 256 B
  __shared__ int acc[NDET];
  __shared__ int kcnt_sh;

  // load sorted keys, decode boxes + class offset + area
  #pragma unroll
  for (int s = 0; s < 2; s++) {
    int j = t + s * 1024;
    unsigned long long key = cand[(size_t)b * CAP + j];
    float bx[4]; int label; float sc;
    key_decode(key, b, reg, props, bx, label, sc);
    float off = (float)label * NMS_OFF;
    float4 ob = {bx[0] + off, bx[1] + off, bx[2] + off, bx[3] + off};
    obox[j] = ob;
    sar[j] = fmaxf(bx[2] - bx[0], 0.0f) * fmaxf(bx[3] - bx[1], 0.0f);
    unsigned long long bal = __ballot(key != 0ull);
    if (lane == 0) keepw[s * 16 + w] = bal;
  }
  __syncthreads();

  int kcount = 0;
  for (int w0 = 0; w0 < KPRE && kcount < NDET; w0 += WCOLS) {
    // ---- step1: suppress window cols by previously accepted boxes ----
    if (w0 > 0 && kcount > 0) {
      if (t < WCOLS) {
        int j = w0 + t;
        unsigned long long kwv = keepw[j >> 6];
        bool alive = (kwv >> (j & 63)) & 1ull;
        if (alive) {
          float4 jb = obox[j];
          float jar = sar[j];
          for (int a = 0; a < kcount; a++) {
            int ii = acc[a];
            float4 ab = obox[ii];
            float ix1 = fmaxf(ab.x, jb.x), iy1 = fmaxf(ab.y, jb.y);
            float ix2 = fminf(ab.z, jb.z), iy2 = fminf(ab.w, jb.w);
            float iw = fmaxf(ix2 - ix1, 0.0f), ih = fmaxf(iy2 - iy1, 0.0f);
            float inter = iw * ih;
            if (inter > 0.0f) {
              float iou = inter / fmaxf(sar[ii] + jar - inter, 1e-9f);
              if (iou > 0.5f) { alive = false; break; }
            }
          }
        }
        unsigned long long bal = __ballot(alive);
        if (lane == 0) keepw[(w0 >> 6) + (t >> 6)] = bal;
      }
      __syncthreads();
    }
    // ---- step2: window-internal suppression bitmask ----
    {
      int r = t >> 2, wd = t & 3;
      int rg = w0 + r;
      float4 rb = obox[rg];
      float rar = sar[rg];
      unsigned long long m = 0;
      int cbase = w0 + wd * 64;
      for (int jj = 0; jj < 64; jj++) {
        int cg = cbase + jj;
        float4 cb = obox[cg];
        float ix1 = fmaxf(rb.x, cb.x), iy1 = fmaxf(rb.y, cb.y);
        float ix2 = fminf(rb.z, cb.z), iy2 = fminf(rb.w, cb.w);
        float iw = fmaxf(ix2 - ix1, 0.0f), ih = fmaxf(iy2 - iy1, 0.0f);
        float inter = iw * ih;
        if (inter > 0.0f && cg > rg) {
          float iou = inter / fmaxf(rar + sar[cg] - inter, 1e-9f);
          if (iou > 0.5f) m |= (1ull << jj);
        }
      }
      mask[r][wd] = m;
    }
    __syncthreads();
    // ---- step3: single-wave serial greedy reduce over the window ----
    if (w == 0) {
      unsigned long long kw0 = keepw[(w0 >> 6) + 0];
      unsigned long long kw1 = keepw[(w0 >> 6) + 1];
      unsigned long long kw2 = keepw[(w0 >> 6) + 2];
      unsigned long long kw3 = keepw[(w0 >> 6) + 3];
      int kc = kcount;
      #pragma unroll
      for (int wq = 0; wq < 4; wq++) {
        unsigned long long cw = (wq == 0) ? kw0 : (wq == 1) ? kw1 : (wq == 2) ? kw2 : kw3;
        if (cw == 0ull) continue;
        for (int rb0 = 0; rb0 < 64 && kc < NDET; rb0 += 4) {
          unsigned long long gbits = (cw >> rb0) & 0xFull;
          int r = wq * 64 + rb0;
          // group prefetch of 4 mask rows (independent LDS reads)
          unsigned long long rm0a = mask[r][0],   rm0b = mask[r][1],   rm0c = mask[r][2],   rm0d = mask[r][3];
          unsigned long long rm1a = mask[r+1][0], rm1b = mask[r+1][1], rm1c = mask[r+1][2], rm1d = mask[r+1][3];
          unsigned long long rm2a = mask[r+2][0], rm2b = mask[r+2][1], rm2c = mask[r+2][2], rm2d = mask[r+2][3];
          unsigned long long rm3a = mask[r+3][0], rm3b = mask[r+3][1], rm3c = mask[r+3][2], rm3d = mask[r+3][3];
          if (gbits == 0ull) continue;
          #pragma unroll
          for (int d = 0; d < 4; d++) {
            unsigned long long cwq = (wq == 0) ? kw0 : (wq == 1) ? kw1 : (wq == 2) ? kw2 : kw3;
            if ((cwq >> (rb0 + d)) & 1ull) {
              if (lane == 0) acc[kc] = w0 + r + d;
              kc++;
              if (kc >= NDET) break;
              unsigned long long ma = (d == 0) ? rm0a : (d == 1) ? rm1a : (d == 2) ? rm2a : rm3a;
              unsigned long long mb = (d == 0) ? rm0b : (d == 1) ? rm1b : (d == 2) ? rm2b : rm3b;
              unsigned long long mc = (d == 0) ? rm0c : (d == 1) ? rm1c : (d == 2) ? rm2c : rm3c;
              unsigned long long md = (d == 0) ? rm0d : (d == 1) ? rm1d : (d == 2) ? rm2d : rm3d;
              kw0 &= ~ma; kw1 &= ~mb; kw2 &= ~mc; kw3 &= ~md;
            }
          }
          cw = (wq == 0) ? kw0 : (wq == 1) ? kw1 : (wq == 2) ? kw2 : kw3;
        }
      }
      if (lane == 0) {
        keepw[(w0 >> 6) + 0] = kw0;
        keepw[(w0 >> 6) + 1] = kw1;
        keepw[(w0 >> 6) + 2] = kw2;
        keepw[(w0 >> 6) + 3] = kw3;
        kcnt_sh = kc;
      }
    }
    __syncthreads();
    kcount = kcnt_sh;
  }

  // rare path: fewer than 100 kept after all windows -> backfill non-kept ascending
  if (t == 0 && kcount < NDET) {
    int run = kcount;
    for (int wq = 0; wq < KPRE / 64 && run < NDET; wq++) {
      unsigned long long nk = ~keepw[wq];
      while (nk && run < NDET) {
        int bit2 = __ffsll((long long)nk) - 1;
        nk &= nk - 1;
        acc[run++] = wq * 64 + bit2;
      }
    }
  }
  __syncthreads();

  if (t < NDET) {
    int k = acc[t];
    bool kept = t < kcount;
    unsigned long long key = cand[(size_t)b * CAP + k];
    float bx[4]; int label; float sc;
    key_decode(key, b, reg, props, bx, label, sc);
    int oi = b * NDET + t;
    out[(size_t)oi * 4 + 0] = bx[0];
    out[(size_t)oi * 4 + 1] = bx[1];
    out[(size_t)oi * 4 + 2] = bx[2];
    out[(size_t)oi * 4 + 3] = bx[3];
    out[Bn * NDET * 4 + oi] = kept ? sc : -1.0f;
    out[Bn * NDET * 5 + oi] = (float)label;
    out[Bn * NDET * 6 + oi] = kept ? 1.0f : 0.0f;
  }
}

extern "C" void kernel_launch(void* const* d_in, const int* in_sizes, int n_in,
                              void* d_out, int out_size, void* d_ws, size_t ws_size,
                              hipStream_t stream) {
  const float* logits = (const float*)d_in[0];
  const float* reg    = (const float*)d_in[1];
  const float* props  = (const float*)d_in[2];
  float* out = (float*)d_out;
  char* ws = (char*)d_ws;

  int*   hist   = (int*)(ws + OFF_HIST);
  int*   cnt    = (int*)(ws + OFF_CNT);
  int*   T      = (int*)(ws + OFF_T);
  int*   bcount = (int*)(ws + OFF_BC);
  int*   boffs  = (int*)(ws + OFF_BO);
  float* scores = (float*)(ws + OFF_SCORE);
  unsigned long long* cand = (unsigned long long*)(ws + OFF_CAND);

  hipMemsetAsync(ws + OFF_HIST, 0, ZERO_BYTES, stream);
  k1_score<<<(Bn * Pn) / 4, 256, 0, stream>>>(logits, reg, props, scores, hist);
  k2_thresh<<<Bn, 256, 0, stream>>>(hist, T);
  k3a_count<<<Bn * BPI, 256, 0, stream>>>(scores, T, bcount);
  k3b_scan<<<Bn, 256, 0, stream>>>(bcount, boffs, cnt);
  k3c_scatter<<<Bn * BPI, 256, 0, stream>>>(scores, T, boffs, cand);
  k4_sort<<<Bn, 1024, 0, stream>>>(cand, cnt);
  k5_nms<<<Bn, 1024, 0, stream>>>(cand, reg, props, out);
}

// Round 4
// 152.971 us; speedup vs baseline: 5.6166x; 1.1535x over previous
//
#include <hip/hip_runtime.h>
#include <cstdint>
#include <cstddef>

typedef unsigned long long u64;

// ---------------- problem constants ----------------
constexpr int Bn   = 8;
constexpr int Pn   = 2000;
constexpr int Cn   = 81;
constexpr int CM1  = 80;
constexpr int Mn   = Pn * CM1;      // 160000 per image
constexpr int KPRE = 2048;
constexpr int NDET = 100;
constexpr int CAP  = 4096;          // candidate cap per image (n ~ 2050)
constexpr int NBINS = 5632;         // score-bits histogram bins
constexpr int BINOFF = (122 << 10); // exponent 122 (scores > 0.05 > 2^-5)
constexpr int NCH  = 64;            // k3 chunks per image
constexpr int CHEL = Mn / NCH;      // 2500 elements per k3 chunk
constexpr int WCOLS = 256;          // NMS window size
constexpr float W_IMG = 1333.0f;
constexpr float H_IMG = 800.0f;
constexpr float XFORM_CLIP = 4.135166556742356f; // log(1000/16)
constexpr float NMS_OFF = 1334.0f;               // max(W,H)+1

// ---------------- ws layout (bytes) ----------------
constexpr size_t OFF_HIST  = 0;                                   // memset to 0
constexpr size_t ZERO_BYTES = (size_t)Bn * NBINS * 4;             // 180224
constexpr size_t OFF_CNT   = ZERO_BYTES;                          // Bn int
constexpr size_t OFF_T     = OFF_CNT + Bn * 4;                    // Bn int
constexpr size_t OFF_BC    = OFF_T + Bn * 4;                      // Bn*NCH int
constexpr size_t OFF_SCORE = OFF_BC + (size_t)Bn * NCH * 4;       // Bn*Mn f32 (5.12 MB)
constexpr size_t OFF_CANDA = OFF_SCORE + (size_t)Bn * Mn * 4;     // Bn*CAP u64
constexpr size_t OFF_CANDB = OFF_CANDA + (size_t)Bn * CAP * 8;    // Bn*CAP u64
constexpr size_t OFF_FINAL = OFF_CANDB + (size_t)Bn * CAP * 8;    // Bn*KPRE u64

__device__ __forceinline__ void decode_clip(const float4 rv, float w, float h,
                                            float cx, float cy, float out[4]) {
  float dx = rv.x / 10.0f;
  float dy = rv.y / 10.0f;
  float dw = fminf(rv.z / 5.0f, XFORM_CLIP);
  float dh = fminf(rv.w / 5.0f, XFORM_CLIP);
  float pcx = dx * w + cx;
  float pcy = dy * h + cy;
  float pw = expf(dw) * w;
  float ph = expf(dh) * h;
  out[0] = fminf(fmaxf(pcx - 0.5f * pw, 0.0f), W_IMG);
  out[1] = fminf(fmaxf(pcy - 0.5f * ph, 0.0f), H_IMG);
  out[2] = fminf(fmaxf(pcx + 0.5f * pw, 0.0f), W_IMG);
  out[3] = fminf(fmaxf(pcy + 0.5f * ph, 0.0f), H_IMG);
}

__device__ __forceinline__ int score_bin(unsigned bits) {
  int bin = (int)(bits >> 13) - BINOFF;
  return min(max(bin, 0), NBINS - 1);
}

// ---------------- K1: softmax + decode + mask + histogram ----------------
__global__ __launch_bounds__(256) void
k1_score(const float* __restrict__ logits, const float* __restrict__ reg,
         const float* __restrict__ props, float* __restrict__ scores,
         int* __restrict__ hist) {
  int wid = blockIdx.x * 4 + (threadIdx.x >> 6);   // proposal id (b*Pn+p)
  int lane = threadIdx.x & 63;
  if (wid >= Bn * Pn) return;
  int b = wid / Pn, p = wid % Pn;

  const float* lg = logits + (size_t)wid * Cn;
  float x0 = lg[lane];
  float x1 = (lane < Cn - 64) ? lg[64 + lane] : -3.4e38f;
  float mx = fmaxf(x0, x1);
  for (int m = 32; m; m >>= 1) mx = fmaxf(mx, __shfl_xor(mx, m, 64));
  float e0 = expf(x0 - mx);
  float e1 = (lane < Cn - 64) ? expf(x1 - mx) : 0.0f;
  float ssum = e0 + e1;
  for (int m = 32; m; m >>= 1) ssum += __shfl_xor(ssum, m, 64);

  const float4 pb = *reinterpret_cast<const float4*>(props + (size_t)wid * 4);
  float w = pb.z - pb.x, h = pb.w - pb.y;
  float cx = pb.x + 0.5f * w, cy = pb.y + 0.5f * h;

  const float* rrow = reg + (size_t)wid * (Cn * 4);
  float* srow = scores + (size_t)b * Mn + (size_t)p * CM1;
  int* hrow = hist + (size_t)b * NBINS;

  #pragma unroll
  for (int slot = 0; slot < 2; slot++) {
    int c = lane + slot * 64;
    float e = slot ? e1 : e0;
    if (c < 1 || c >= Cn) continue;
    float sc = e / ssum;
    float4 rv = *reinterpret_cast<const float4*>(rrow + c * 4);
    float bx[4];
    decode_clip(rv, w, h, cx, cy, bx);
    bool valid = (sc > 0.05f) && (bx[2] - bx[0] >= 0.01f) && (bx[3] - bx[1] >= 0.01f);
    srow[c - 1] = valid ? sc : -1.0f;
    if (valid) atomicAdd(&hrow[score_bin(__float_as_uint(sc))], 1);
  }
}

// ---------------- K2: per-image bin threshold ----------------
__global__ __launch_bounds__(256) void
k2_thresh(const int* __restrict__ hist, int* __restrict__ T) {
  int b = blockIdx.x, t = threadIdx.x;
  __shared__ int partial[256];
  __shared__ int sufAfter[256];
  __shared__ int tmax;
  const int CH = NBINS / 256;  // 22
  const int* hrow = hist + (size_t)b * NBINS;
  int lo = t * CH, hi = lo + CH;
  int s = 0;
  for (int i = lo; i < hi; i++) s += hrow[i];
  partial[t] = s;
  if (t == 0) tmax = 0;
  __syncthreads();
  if (t == 0) {
    int acc = 0;
    for (int q = 255; q >= 0; q--) { sufAfter[q] = acc; acc += partial[q]; }
  }
  __syncthreads();
  int cum = sufAfter[t];
  int cand = -1;
  for (int i = hi - 1; i >= lo; i--) {
    cum += hrow[i];
    if (cum >= KPRE) { cand = i; break; }
  }
  if (cand >= 0) atomicMax(&tmax, cand);
  __syncthreads();
  if (t == 0) T[b] = tmax;
}

// ---------------- K3a: per-chunk candidate count ----------------
__global__ __launch_bounds__(256) void
k3a_count(const float* __restrict__ scores, const int* __restrict__ T,
          int* __restrict__ bcount) {
  int blk = blockIdx.x, t = threadIdx.x, lane = t & 63, w = t >> 6;
  int b = blk / NCH, c = blk % NCH;
  int Tb = T[b];
  int cntl = 0;
  #pragma unroll
  for (int it = 0; it < 10; it++) {
    int il = it * 256 + t;
    if (il < CHEL) {
      float sc = scores[(size_t)b * Mn + c * CHEL + il];
      if (sc > 0.0f && score_bin(__float_as_uint(sc)) >= Tb) cntl++;
    }
  }
  for (int s = 32; s; s >>= 1) cntl += __shfl_xor(cntl, s, 64);
  __shared__ int wsum[4];
  if (lane == 0) wsum[w] = cntl;
  __syncthreads();
  if (t == 0) bcount[blk] = wsum[0] + wsum[1] + wsum[2] + wsum[3];
}

// ---------------- K3c: in-kernel scan of chunk counts + scatter ----------------
__global__ __launch_bounds__(256) void
k3c_scatter(const float* __restrict__ scores, const int* __restrict__ T,
            const int* __restrict__ bcount, int* __restrict__ cnt,
            u64* __restrict__ candA) {
  int blk = blockIdx.x, t = threadIdx.x, lane = t & 63, w = t >> 6;
  int b = blk / NCH, c = blk % NCH;
  __shared__ int sbase;
  __shared__ int wc[4];
  if (t < 64) {
    int v = bcount[b * NCH + t];
    int incl = v;
    for (int s = 1; s < 64; s <<= 1) {
      int y = __shfl_up(incl, s, 64);
      if (t >= s) incl += y;
    }
    int excl = incl - v;
    int basec = __shfl(excl, c, 64);
    int total = __shfl(incl, 63, 64);
    if (t == 0) {
      sbase = basec;
      if (c == NCH - 1) cnt[b] = total;
    }
  }
  __syncthreads();
  int base = sbase;
  int Tb = T[b];
  for (int it = 0; it < 10; it++) {
    int il = it * 256 + t;
    int m = c * CHEL + il;
    bool pass = false;
    unsigned bits = 0;
    if (il < CHEL) {
      float sc = scores[(size_t)b * Mn + m];
      bits = __float_as_uint(sc);
      pass = (sc > 0.0f) && (score_bin(bits) >= Tb);
    }
    u64 bal = __ballot(pass);
    if (lane == 0) wc[w] = __popcll(bal);
    __syncthreads();
    int off = base;
    for (int q = 0; q < w; q++) off += wc[q];
    int tot = wc[0] + wc[1] + wc[2] + wc[3];
    int rank = __popcll(bal & ((1ull << lane) - 1ull));
    int pos = off + rank;
    if (pass && pos < CAP)
      candA[(size_t)b * CAP + pos] =
          ((u64)bits << 32) | (unsigned)(0xFFFFFFFFu - (unsigned)m);
    base += tot;
    __syncthreads();
  }
}

// ---------------- K4a: per-chunk bitonic sort (512 elems, desc) ----------------
__global__ __launch_bounds__(256) void
k4a_chunk(u64* __restrict__ candA, const int* __restrict__ cnt) {
  __shared__ u64 sk[512];  // 4 KB
  int blk = blockIdx.x, t = threadIdx.x;
  int b = blk >> 3, ch = blk & 7;
  int n = min(cnt[b], CAP);
  int base = ch * 512;
  #pragma unroll
  for (int i = t; i < 512; i += 256) {
    int g = base + i;
    sk[i] = (g < n) ? candA[(size_t)b * CAP + g] : 0ull;
  }
  __syncthreads();
  for (int k = 2; k <= 512; k <<= 1) {
    for (int j = k >> 1; j > 0; j >>= 1) {
      #pragma unroll
      for (int i = t; i < 512; i += 256) {
        int ixj = i ^ j;
        if (ixj > i) {
          u64 a = sk[i], c2 = sk[ixj];
          bool dir = ((i & k) == 0);  // descending overall
          if ((a < c2) == dir) { sk[i] = c2; sk[ixj] = a; }
        }
      }
      __syncthreads();
    }
  }
  #pragma unroll
  for (int i = t; i < 512; i += 256)
    candA[(size_t)b * CAP + base + i] = sk[i];
}

// ---------------- K4b: merge-path pairwise merge (desc, A-priority) ----------
// Merges contiguous pair [A | B] (each LA elems) -> out[0..LOUT). Exact.
__global__ __launch_bounds__(256) void
k4b_merge(const u64* __restrict__ in, u64* __restrict__ out, int LA, int LOUT,
          int mPerImg, int inImgStride, int outImgStride) {
  extern __shared__ u64 sm[];
  int blk = blockIdx.x, t = threadIdx.x;
  int b = blk / mPerImg, m = blk % mPerImg;
  const u64* A = in + (size_t)b * inImgStride + (size_t)m * 2 * LA;
  u64* O = out + (size_t)b * outImgStride + (size_t)m * LOUT;
  int LB = LA, LT = 2 * LA;
  for (int i = t; i < LT; i += 256) sm[i] = A[i];
  __syncthreads();
  const u64* sA = sm;
  const u64* sB = sm + LA;
  int CH = LOUT / 256;
  int d = t * CH;
  int lo = max(0, d - LB), hi = min(d, LA);
  while (lo < hi) {
    int mid = (lo + hi) >> 1;
    if (sA[mid] >= sB[d - 1 - mid]) lo = mid + 1; else hi = mid;
  }
  int i = lo, j = d - lo;
  for (int e = 0; e < CH; e++) {
    u64 v;
    if (j >= LB || (i < LA && sA[i] >= sB[j])) v = sA[i++];
    else v = sB[j++];
    O[d + e] = v;
  }
}

// decode a candidate key into raw clipped box + label + score
__device__ __forceinline__ void key_decode(u64 key, int b,
                                           const float* __restrict__ reg,
                                           const float* __restrict__ props,
                                           float bx[4], int& label, float& sc) {
  sc = __uint_as_float((unsigned)(key >> 32));
  bx[0] = bx[1] = bx[2] = bx[3] = 0.0f;
  label = 0;
  if (key != 0ull) {
    int m = (int)(0xFFFFFFFFu - (unsigned)key);
    int p = m / CM1;
    int c = m - p * CM1 + 1;
    int nidx = b * Pn + p;
    const float4 pb = *reinterpret_cast<const float4*>(props + (size_t)nidx * 4);
    float w = pb.z - pb.x, h = pb.w - pb.y;
    float cx = pb.x + 0.5f * w, cy = pb.y + 0.5f * h;
    float4 rv = *reinterpret_cast<const float4*>(reg + (size_t)nidx * (Cn * 4) + c * 4);
    decode_clip(rv, w, h, cx, cy, bx);
    label = c;
  }
}

// ---------------- K5: windowed bitmask NMS + output ----------------
__global__ __launch_bounds__(1024) void
k5_nms(const u64* __restrict__ fin,
       const float* __restrict__ reg, const float* __restrict__ props,
       float* __restrict__ out) {
  int b = blockIdx.x, t = threadIdx.x, lane = t & 63, w = t >> 6;
  __shared__ float4 obox[KPRE];                    // offset boxes, 32 KB
  __shared__ float  sar[KPRE];                     // areas, 8 KB
  __shared__ u64 mask[WCOLS][4];                   // 8 KB
  __shared__ u64 keepw[KPRE / 64];                 // 256 B
  __shared__ int acc[NDET];
  __shared__ int kcnt_sh;

  #pragma unroll
  for (int s = 0; s < 2; s++) {
    int j = t + s * 1024;
    u64 key = fin[(size_t)b * KPRE + j];
    float bx[4]; int label; float sc;
    key_decode(key, b, reg, props, bx, label, sc);
    float off = (float)label * NMS_OFF;
    float4 ob = {bx[0] + off, bx[1] + off, bx[2] + off, bx[3] + off};
    obox[j] = ob;
    sar[j] = fmaxf(bx[2] - bx[0], 0.0f) * fmaxf(bx[3] - bx[1], 0.0f);
    u64 bal = __ballot(key != 0ull);
    if (lane == 0) keepw[s * 16 + w] = bal;
  }
  __syncthreads();

  int kcount = 0;
  for (int w0 = 0; w0 < KPRE && kcount < NDET; w0 += WCOLS) {
    // ---- step1: suppress window cols by previously accepted boxes ----
    if (w0 > 0 && kcount > 0) {
      if (t < WCOLS) {
        int j = w0 + t;
        u64 kwv = keepw[j >> 6];
        bool alive = (kwv >> (j & 63)) & 1ull;
        if (alive) {
          float4 jb = obox[j];
          float jar = sar[j];
          for (int a = 0; a < kcount; a++) {
            int ii = acc[a];
            float4 ab = obox[ii];
            float ix1 = fmaxf(ab.x, jb.x), iy1 = fmaxf(ab.y, jb.y);
            float ix2 = fminf(ab.z, jb.z), iy2 = fminf(ab.w, jb.w);
            float iw = fmaxf(ix2 - ix1, 0.0f), ih = fmaxf(iy2 - iy1, 0.0f);
            float inter = iw * ih;
            if (inter > 0.0f) {
              float iou = inter / fmaxf(sar[ii] + jar - inter, 1e-9f);
              if (iou > 0.5f) { alive = false; break; }
            }
          }
        }
        u64 bal = __ballot(alive);
        if (lane == 0) keepw[(w0 >> 6) + (t >> 6)] = bal;
      }
      __syncthreads();
    }
    // ---- step2: window-internal suppression bitmask ----
    {
      int r = t >> 2, wd = t & 3;
      int rg = w0 + r;
      float4 rb = obox[rg];
      float rar = sar[rg];
      u64 m = 0;
      int cbase = w0 + wd * 64;
      for (int jj = 0; jj < 64; jj++) {
        int cg = cbase + jj;
        float4 cb = obox[cg];
        float ix1 = fmaxf(rb.x, cb.x), iy1 = fmaxf(rb.y, cb.y);
        float ix2 = fminf(rb.z, cb.z), iy2 = fminf(rb.w, cb.w);
        float iw = fmaxf(ix2 - ix1, 0.0f), ih = fmaxf(iy2 - iy1, 0.0f);
        float inter = iw * ih;
        if (inter > 0.0f && cg > rg) {
          float iou = inter / fmaxf(rar + sar[cg] - inter, 1e-9f);
          if (iou > 0.5f) m |= (1ull << jj);
        }
      }
      mask[r][wd] = m;
    }
    __syncthreads();
    // ---- step3: single-wave serial greedy reduce over the window ----
    if (w == 0) {
      u64 kw0 = keepw[(w0 >> 6) + 0];
      u64 kw1 = keepw[(w0 >> 6) + 1];
      u64 kw2 = keepw[(w0 >> 6) + 2];
      u64 kw3 = keepw[(w0 >> 6) + 3];
      int kc = kcount;
      #pragma unroll
      for (int wq = 0; wq < 4; wq++) {
        u64 cw = (wq == 0) ? kw0 : (wq == 1) ? kw1 : (wq == 2) ? kw2 : kw3;
        if (cw == 0ull) continue;
        for (int rb0 = 0; rb0 < 64 && kc < NDET; rb0 += 4) {
          u64 gbits = (cw >> rb0) & 0xFull;
          int r = wq * 64 + rb0;
          u64 rm0a = mask[r][0],   rm0b = mask[r][1],   rm0c = mask[r][2],   rm0d = mask[r][3];
          u64 rm1a = mask[r+1][0], rm1b = mask[r+1][1], rm1c = mask[r+1][2], rm1d = mask[r+1][3];
          u64 rm2a = mask[r+2][0], rm2b = mask[r+2][1], rm2c = mask[r+2][2], rm2d = mask[r+2][3];
          u64 rm3a = mask[r+3][0], rm3b = mask[r+3][1], rm3c = mask[r+3][2], rm3d = mask[r+3][3];
          if (gbits == 0ull) continue;
          #pragma unroll
          for (int d = 0; d < 4; d++) {
            u64 cwq = (wq == 0) ? kw0 : (wq == 1) ? kw1 : (wq == 2) ? kw2 : kw3;
            if ((cwq >> (rb0 + d)) & 1ull) {
              if (lane == 0) acc[kc] = w0 + r + d;
              kc++;
              if (kc >= NDET) break;
              u64 ma = (d == 0) ? rm0a : (d == 1) ? rm1a : (d == 2) ? rm2a : rm3a;
              u64 mb = (d == 0) ? rm0b : (d == 1) ? rm1b : (d == 2) ? rm2b : rm3b;
              u64 mc = (d == 0) ? rm0c : (d == 1) ? rm1c : (d == 2) ? rm2c : rm3c;
              u64 md = (d == 0) ? rm0d : (d == 1) ? rm1d : (d == 2) ? rm2d : rm3d;
              kw0 &= ~ma; kw1 &= ~mb; kw2 &= ~mc; kw3 &= ~md;
            }
          }
          cw = (wq == 0) ? kw0 : (wq == 1) ? kw1 : (wq == 2) ? kw2 : kw3;
        }
      }
      if (lane == 0) {
        keepw[(w0 >> 6) + 0] = kw0;
        keepw[(w0 >> 6) + 1] = kw1;
        keepw[(w0 >> 6) + 2] = kw2;
        keepw[(w0 >> 6) + 3] = kw3;
        kcnt_sh = kc;
      }
    }
    __syncthreads();
    kcount = kcnt_sh;
  }

  if (t == 0 && kcount < NDET) {
    int run = kcount;
    for (int wq = 0; wq < KPRE / 64 && run < NDET; wq++) {
      u64 nk = ~keepw[wq];
      while (nk && run < NDET) {
        int bit2 = __ffsll((long long)nk) - 1;
        nk &= nk - 1;
        acc[run++] = wq * 64 + bit2;
      }
    }
  }
  __syncthreads();

  if (t < NDET) {
    int k = acc[t];
    bool kept = t < kcount;
    u64 key = fin[(size_t)b * KPRE + k];
    float bx[4]; int label; float sc;
    key_decode(key, b, reg, props, bx, label, sc);
    int oi = b * NDET + t;
    out[(size_t)oi * 4 + 0] = bx[0];
    out[(size_t)oi * 4 + 1] = bx[1];
    out[(size_t)oi * 4 + 2] = bx[2];
    out[(size_t)oi * 4 + 3] = bx[3];
    out[Bn * NDET * 4 + oi] = kept ? sc : -1.0f;
    out[Bn * NDET * 5 + oi] = (float)label;
    out[Bn * NDET * 6 + oi] = kept ? 1.0f : 0.0f;
  }
}

extern "C" void kernel_launch(void* const* d_in, const int* in_sizes, int n_in,
                              void* d_out, int out_size, void* d_ws, size_t ws_size,
                              hipStream_t stream) {
  const float* logits = (const float*)d_in[0];
  const float* reg    = (const float*)d_in[1];
  const float* props  = (const float*)d_in[2];
  float* out = (float*)d_out;
  char* ws = (char*)d_ws;

  int*   hist   = (int*)(ws + OFF_HIST);
  int*   cnt    = (int*)(ws + OFF_CNT);
  int*   T      = (int*)(ws + OFF_T);
  int*   bcount = (int*)(ws + OFF_BC);
  float* scores = (float*)(ws + OFF_SCORE);
  u64*   candA  = (u64*)(ws + OFF_CANDA);
  u64*   candB  = (u64*)(ws + OFF_CANDB);
  u64*   fin    = (u64*)(ws + OFF_FINAL);

  hipMemsetAsync(ws + OFF_HIST, 0, ZERO_BYTES, stream);
  k1_score<<<(Bn * Pn) / 4, 256, 0, stream>>>(logits, reg, props, scores, hist);
  k2_thresh<<<Bn, 256, 0, stream>>>(hist, T);
  k3a_count<<<Bn * NCH, 256, 0, stream>>>(scores, T, bcount);
  k3c_scatter<<<Bn * NCH, 256, 0, stream>>>(scores, T, bcount, cnt, candA);
  k4a_chunk<<<Bn * 8, 256, 0, stream>>>(candA, cnt);
  // R1: 8x512 -> 4x1024 per image
  k4b_merge<<<Bn * 4, 256, 1024 * 8, stream>>>(candA, candB, 512, 1024, 4, CAP, CAP);
  // R2: 4x1024 -> 2x2048 per image
  k4b_merge<<<Bn * 2, 256, 2048 * 8, stream>>>(candB, candA, 1024, 2048, 2, CAP, CAP);
  // R3: 2x2048 -> top-2048 per image
  k4b_merge<<<Bn * 1, 256, 4096 * 8, stream>>>(candA, fin, 2048, 2048, 1, CAP, KPRE);
  k5_nms<<<Bn, 1024, 0, stream>>>(fin, reg, props, out);
}